// Round 14
// baseline (39.084 us; speedup 1.0000x reference)
//
#include <hip/hip_runtime.h>

#define N 384
#define DXD 128
#define DZD 32
#define NPAIR (N / 2)              // 192 b-pairs
#define NORM (2.0f / 1443840.0f)   // 2 / (n*K*(2n-3K-1)), n=384, K=5
#define CX 24.0f                   // exponent centers (cancel in sigma ratio)
#define CZ 12.0f

// ---------------------------------------------------------------------------
// Kernel A: LDS-tiled transpose, coalesced both sides; zeroes out[0].
__global__ void __launch_bounds__(256) transpose_xz(const float* __restrict__ X,
                                                    const float* __restrict__ Z,
                                                    float* __restrict__ XT,
                                                    float* __restrict__ ZT,
                                                    float* __restrict__ out) {
    __shared__ float tile[64][129];
    const int b = blockIdx.x;
    const int t = threadIdx.x;
    if (b == 0 && t == 0) out[0] = 0.f;

    if (b < 6) {
        const int R = b * 64;
        #pragma unroll
        for (int r0 = 0; r0 < 64; r0 += 8) {
            const int r = r0 + (t >> 5);
            const int c = (t & 31) * 4;
            float4 v = *reinterpret_cast<const float4*>(X + (size_t)(R + r) * DXD + c);
            tile[r][c] = v.x; tile[r][c + 1] = v.y; tile[r][c + 2] = v.z; tile[r][c + 3] = v.w;
        }
        __syncthreads();
        const int l = t & 63, w = t >> 6;
        #pragma unroll
        for (int k0 = 0; k0 < DXD; k0 += 4)
            XT[(size_t)(k0 + w) * N + R + l] = tile[l][k0 + w];
    } else {
        const int R = (b - 6) * 64;
        #pragma unroll
        for (int r0 = 0; r0 < 64; r0 += 32) {
            const int r = r0 + (t >> 3);
            const int c = (t & 7) * 4;
            float4 v = *reinterpret_cast<const float4*>(Z + (size_t)(R + r) * DZD + c);
            tile[r][c] = v.x; tile[r][c + 1] = v.y; tile[r][c + 2] = v.z; tile[r][c + 3] = v.w;
        }
        __syncthreads();
        const int l = t & 63, w = t >> 6;
        #pragma unroll
        for (int k0 = 0; k0 < DZD; k0 += 4)
            ZT[(size_t)(k0 + w) * N + R + l] = tile[l][k0 + w];
    }
}

// ---------------------------------------------------------------------------
// Kernel B: one block per row i. Build e-tables (coalesced XT/ZT reads,
// wave-uniform X_i/Z_i), write EX/EZ, and the PACKED pair table:
// PACK[i*NPAIR+p] = (Px, Sx, Pz, Sz) with P=e0*e1, S=e0+e1 for pair p.
__global__ void __launch_bounds__(192) exp_pairs(const float* __restrict__ X,
                                                 const float* __restrict__ Z,
                                                 const float* __restrict__ XT,
                                                 const float* __restrict__ ZT,
                                                 float* __restrict__ EX,
                                                 float* __restrict__ EZ,
                                                 float4* __restrict__ PACK) {
    __shared__ float ex[N];
    __shared__ float ez[N];
    const int i = blockIdx.x;
    const int t = threadIdx.x;

    const float* __restrict__ Xi = X + (size_t)i * DXD;
    const float* __restrict__ Zi = Z + (size_t)i * DZD;

    #pragma unroll
    for (int rep = 0; rep < 2; ++rep) {
        const int a = rep * 192 + t;
        float sq = 0.f;
        #pragma unroll 16
        for (int k = 0; k < DXD; ++k) {
            float v = XT[(size_t)k * N + a] - Xi[k];   // coalesced across lanes
            sq += v * v;
        }
        float dx = (sq > 1e-12f) ? sqrtf(sq) : 0.f;
        float exv = __expf(2.f * dx - CX);
        ex[a] = exv;
        EX[(size_t)i * N + a] = exv;

        float sqz = 0.f;
        #pragma unroll 16
        for (int k = 0; k < DZD; ++k) {
            float v = ZT[(size_t)k * N + a] - Zi[k];
            sqz += v * v;
        }
        float dz = (sqz > 1e-12f) ? sqrtf(sqz) : 0.f;
        float ezv = __expf(2.f * dz - CZ);
        ez[a] = ezv;
        EZ[(size_t)i * N + a] = ezv;
    }
    __syncthreads();

    // pair p = t: PACK entry serves X and Z both; float4 store coalesced.
    float e0 = ex[2 * t], e1 = ex[2 * t + 1];
    float f0 = ez[2 * t], f1 = ez[2 * t + 1];
    PACK[(size_t)i * NPAIR + t] = make_float4(e0 * e1, e0 + e1, f0 * f1, f0 + f1);
}

// ---------------------------------------------------------------------------
// Kernel C: loss. sigma_p + sigma_q = (t0 + P) / (t0 + ea^2), t0 = fma(ea,S,P).
// PACK reads are block-uniform (no threadIdx in address) -> scalar-load
// eligible (SMEM pipe); zero LDS. 8 independent rcp chains. 1 atomic/block.
__global__ void __launch_bounds__(192) loss_k(const float* __restrict__ EX,
                                              const float* __restrict__ EZ,
                                              const float4* __restrict__ PACK,
                                              float* __restrict__ out) {
    __shared__ float red[3];
    const int i = blockIdx.x >> 1;
    const int t = threadIdx.x;
    const int a = (blockIdx.x & 1) * 192 + t;

    const float ea = EX[(size_t)i * N + a], ea2 = ea * ea;   // coalesced
    const float fa = EZ[(size_t)i * N + a], fa2 = fa * fa;

    const float4* __restrict__ pk = PACK + (size_t)i * NPAIR;  // uniform base
    float ax0 = 0.f, ax1 = 0.f, ax2 = 0.f, ax3 = 0.f;
    float az0 = 0.f, az1 = 0.f, az2 = 0.f, az3 = 0.f;
    #pragma unroll 4
    for (int p = 0; p < NPAIR; p += 4) {
        float4 c0 = pk[p + 0];     // (Px, Sx, Pz, Sz) -- uniform address
        float4 c1 = pk[p + 1];
        float4 c2 = pk[p + 2];
        float4 c3 = pk[p + 3];
        float t0;
        t0 = fmaf(ea, c0.y, c0.x); ax0 += (t0 + c0.x) * __builtin_amdgcn_rcpf(t0 + ea2);
        t0 = fmaf(fa, c0.w, c0.z); az0 += (t0 + c0.z) * __builtin_amdgcn_rcpf(t0 + fa2);
        t0 = fmaf(ea, c1.y, c1.x); ax1 += (t0 + c1.x) * __builtin_amdgcn_rcpf(t0 + ea2);
        t0 = fmaf(fa, c1.w, c1.z); az1 += (t0 + c1.z) * __builtin_amdgcn_rcpf(t0 + fa2);
        t0 = fmaf(ea, c2.y, c2.x); ax2 += (t0 + c2.x) * __builtin_amdgcn_rcpf(t0 + ea2);
        t0 = fmaf(fa, c2.w, c2.z); az2 += (t0 + c2.z) * __builtin_amdgcn_rcpf(t0 + fa2);
        t0 = fmaf(ea, c3.y, c3.x); ax3 += (t0 + c3.x) * __builtin_amdgcn_rcpf(t0 + ea2);
        t0 = fmaf(fa, c3.w, c3.z); az3 += (t0 + c3.z) * __builtin_amdgcn_rcpf(t0 + fa2);
    }
    float sx = (ax0 + ax1) + (ax2 + ax3);    // = sum_b sigmoid_X
    float sz = (az0 + az1) + (az2 + az3);    // = sum_b sigmoid_Z

    // intrusion = relu(1+sx-K); W = clamp((K+1-(1+sz))/K, 0, 1)
    float intr = fmaxf(sx - 4.f, 0.f);
    float W = fminf(fmaxf((5.f - sz) * 0.2f, 0.f), 1.f);
    float contrib = intr * (1.f - W);

    #pragma unroll
    for (int off = 32; off > 0; off >>= 1)
        contrib += __shfl_down(contrib, off, 64);
    const int lane = t & 63, w = t >> 6;
    if (lane == 0) red[w] = contrib;
    __syncthreads();
    if (t == 0) atomicAdd(out, (red[0] + red[1] + red[2]) * NORM);
}

extern "C" void kernel_launch(void* const* d_in, const int* in_sizes, int n_in,
                              void* d_out, int out_size, void* d_ws, size_t ws_size,
                              hipStream_t stream) {
    const float* X = (const float*)d_in[0];   // (384, 128) f32
    const float* Z = (const float*)d_in[1];   // (384, 32)  f32
    float* out = (float*)d_out;

    float* XT = (float*)d_ws;                  // 128*384
    float* ZT = XT + (size_t)DXD * N;          // 32*384
    float* EX = ZT + (size_t)DZD * N;          // 384*384
    float* EZ = EX + (size_t)N * N;            // 384*384
    float4* PACK = (float4*)(EZ + (size_t)N * N);  // 384*192 float4

    transpose_xz<<<12, 256, 0, stream>>>(X, Z, XT, ZT, out);
    exp_pairs<<<N, 192, 0, stream>>>(X, Z, XT, ZT, EX, EZ, PACK);
    loss_k<<<2 * N, 192, 0, stream>>>(EX, EZ, PACK, out);
}

// Round 15
// 38.918 us; speedup vs baseline: 1.0043x; 1.0043x over previous
//
#include <hip/hip_runtime.h>

#define N 384
#define DXD 128
#define DZD 32
#define NQUAD 96                   // 96 quads of 4 b's per matrix
#define NORM (2.0f / 1443840.0f)   // 2 / (n*K*(2n-3K-1)), n=384, K=5
#define CX 24.0f                   // exponent centers (cancel in sigma ratio)
#define CZ 12.0f

// ---------------------------------------------------------------------------
// Kernel A: LDS-tiled transpose, coalesced both sides; zeroes out[0].
__global__ void __launch_bounds__(256) transpose_xz(const float* __restrict__ X,
                                                    const float* __restrict__ Z,
                                                    float* __restrict__ XT,
                                                    float* __restrict__ ZT,
                                                    float* __restrict__ out) {
    __shared__ float tile[64][129];
    const int b = blockIdx.x;
    const int t = threadIdx.x;
    if (b == 0 && t == 0) out[0] = 0.f;

    if (b < 6) {
        const int R = b * 64;
        #pragma unroll
        for (int r0 = 0; r0 < 64; r0 += 8) {
            const int r = r0 + (t >> 5);
            const int c = (t & 31) * 4;
            float4 v = *reinterpret_cast<const float4*>(X + (size_t)(R + r) * DXD + c);
            tile[r][c] = v.x; tile[r][c + 1] = v.y; tile[r][c + 2] = v.z; tile[r][c + 3] = v.w;
        }
        __syncthreads();
        const int l = t & 63, w = t >> 6;
        #pragma unroll
        for (int k0 = 0; k0 < DXD; k0 += 4)
            XT[(size_t)(k0 + w) * N + R + l] = tile[l][k0 + w];
    } else {
        const int R = (b - 6) * 64;
        #pragma unroll
        for (int r0 = 0; r0 < 64; r0 += 32) {
            const int r = r0 + (t >> 3);
            const int c = (t & 7) * 4;
            float4 v = *reinterpret_cast<const float4*>(Z + (size_t)(R + r) * DZD + c);
            tile[r][c] = v.x; tile[r][c + 1] = v.y; tile[r][c + 2] = v.z; tile[r][c + 3] = v.w;
        }
        __syncthreads();
        const int l = t & 63, w = t >> 6;
        #pragma unroll
        for (int k0 = 0; k0 < DZD; k0 += 4)
            ZT[(size_t)(k0 + w) * N + R + l] = tile[l][k0 + w];
    }
}

// ---------------------------------------------------------------------------
// Kernel B: once per row i: e-tables -> EX/EZ (global, coalesced) and
// quad-packed pair tables PACKX[i][q] = (P0,S0,P1,S1) for pairs (4q,4q+1),
// (4q+2,4q+3), with P=e0*e1, S=e0+e1. Same for Z.
__global__ void __launch_bounds__(192) exp_pairs(const float* __restrict__ X,
                                                 const float* __restrict__ Z,
                                                 const float* __restrict__ XT,
                                                 const float* __restrict__ ZT,
                                                 float* __restrict__ EX,
                                                 float* __restrict__ EZ,
                                                 float4* __restrict__ PACKX,
                                                 float4* __restrict__ PACKZ) {
    __shared__ float ex[N] __attribute__((aligned(16)));
    __shared__ float ez[N] __attribute__((aligned(16)));
    const int i = blockIdx.x;
    const int t = threadIdx.x;

    const float* __restrict__ Xi = X + (size_t)i * DXD;   // uniform -> scalar path
    const float* __restrict__ Zi = Z + (size_t)i * DZD;

    #pragma unroll
    for (int rep = 0; rep < 2; ++rep) {
        const int a = rep * 192 + t;
        float sq = 0.f;
        #pragma unroll 16
        for (int k = 0; k < DXD; ++k) {
            float v = XT[(size_t)k * N + a] - Xi[k];   // coalesced across lanes
            sq += v * v;
        }
        float dx = (sq > 1e-12f) ? sqrtf(sq) : 0.f;
        float exv = __expf(2.f * dx - CX);
        ex[a] = exv;
        EX[(size_t)i * N + a] = exv;

        float sqz = 0.f;
        #pragma unroll 16
        for (int k = 0; k < DZD; ++k) {
            float v = ZT[(size_t)k * N + a] - Zi[k];
            sqz += v * v;
        }
        float dz = (sqz > 1e-12f) ? sqrtf(sqz) : 0.f;
        float ezv = __expf(2.f * dz - CZ);
        ez[a] = ezv;
        EZ[(size_t)i * N + a] = ezv;
    }
    __syncthreads();

    if (t < NQUAD) {
        const int q = t;
        float e0 = ex[4 * q], e1 = ex[4 * q + 1], e2 = ex[4 * q + 2], e3 = ex[4 * q + 3];
        PACKX[(size_t)i * NQUAD + q] = make_float4(e0 * e1, e0 + e1, e2 * e3, e2 + e3);
    } else {
        const int q = t - NQUAD;
        float f0 = ez[4 * q], f1 = ez[4 * q + 1], f2 = ez[4 * q + 2], f3 = ez[4 * q + 3];
        PACKZ[(size_t)i * NQUAD + q] = make_float4(f0 * f1, f0 + f1, f2 * f3, f2 + f3);
    }
}

// ---------------------------------------------------------------------------
// Kernel C: loss with register quad-combine: for pair j, d_j = P_j + S_j*ea
// + ea^2, n_j = P_j + (P_j + S_j*ea); sum of 4 sigmoids =
// (n1*d2 + n2*d1) / (d1*d2)  -> 11 VALU + 1 rcp per 4 sigmoids.
// Tables staged in LDS (3 KB), b-loop reads uniform -> broadcast.
__global__ void __launch_bounds__(192) loss_k(const float* __restrict__ EX,
                                              const float* __restrict__ EZ,
                                              const float4* __restrict__ PACKX,
                                              const float4* __restrict__ PACKZ,
                                              float* __restrict__ out) {
    __shared__ float4 px[NQUAD];
    __shared__ float4 pz[NQUAD];
    __shared__ float red[3];
    const int i = blockIdx.x >> 1;
    const int t = threadIdx.x;
    const int a = (blockIdx.x & 1) * 192 + t;

    if (t < NQUAD) px[t] = PACKX[(size_t)i * NQUAD + t];
    else           pz[t - NQUAD] = PACKZ[(size_t)i * NQUAD + (t - NQUAD)];
    const float ea = EX[(size_t)i * N + a];   // coalesced
    const float fa = EZ[(size_t)i * N + a];
    const float ea2 = ea * ea, fa2 = fa * fa;
    __syncthreads();

    float ax0 = 0.f, ax1 = 0.f, ax2 = 0.f, ax3 = 0.f;
    float az0 = 0.f, az1 = 0.f, az2 = 0.f, az3 = 0.f;

#define QUAD(c, s, s2, acc)                                                   \
    {                                                                         \
        float t1 = fmaf(s, c.y, c.x), t2 = fmaf(s, c.w, c.z);                 \
        float d1 = t1 + s2, d2 = t2 + s2;                                     \
        float n1 = t1 + c.x, n2 = t2 + c.z;                                   \
        float D = d1 * d2;                                                    \
        float Nn = fmaf(n2, d1, n1 * d2);                                     \
        acc = fmaf(Nn, __builtin_amdgcn_rcpf(D), acc);                        \
    }

    #pragma unroll 2
    for (int q = 0; q < NQUAD; q += 4) {     // 24 outer iters x 8 quads
        float4 cx0 = px[q + 0];              // uniform -> LDS broadcast
        float4 cx1 = px[q + 1];
        float4 cx2 = px[q + 2];
        float4 cx3 = px[q + 3];
        float4 cz0 = pz[q + 0];
        float4 cz1 = pz[q + 1];
        float4 cz2 = pz[q + 2];
        float4 cz3 = pz[q + 3];
        QUAD(cx0, ea, ea2, ax0)
        QUAD(cz0, fa, fa2, az0)
        QUAD(cx1, ea, ea2, ax1)
        QUAD(cz1, fa, fa2, az1)
        QUAD(cx2, ea, ea2, ax2)
        QUAD(cz2, fa, fa2, az2)
        QUAD(cx3, ea, ea2, ax3)
        QUAD(cz3, fa, fa2, az3)
    }
#undef QUAD
    float sx = (ax0 + ax1) + (ax2 + ax3);    // = sum_b sigmoid_X
    float sz = (az0 + az1) + (az2 + az3);    // = sum_b sigmoid_Z

    // intrusion = relu(1+sx-K); W = clamp((K+1-(1+sz))/K, 0, 1)
    float intr = fmaxf(sx - 4.f, 0.f);
    float W = fminf(fmaxf((5.f - sz) * 0.2f, 0.f), 1.f);
    float contrib = intr * (1.f - W);

    #pragma unroll
    for (int off = 32; off > 0; off >>= 1)
        contrib += __shfl_down(contrib, off, 64);
    const int lane = t & 63, w = t >> 6;
    if (lane == 0) red[w] = contrib;
    __syncthreads();
    if (t == 0) atomicAdd(out, (red[0] + red[1] + red[2]) * NORM);
}

extern "C" void kernel_launch(void* const* d_in, const int* in_sizes, int n_in,
                              void* d_out, int out_size, void* d_ws, size_t ws_size,
                              hipStream_t stream) {
    const float* X = (const float*)d_in[0];   // (384, 128) f32
    const float* Z = (const float*)d_in[1];   // (384, 32)  f32
    float* out = (float*)d_out;

    float* XT = (float*)d_ws;                      // 128*384
    float* ZT = XT + (size_t)DXD * N;              // 32*384
    float* EX = ZT + (size_t)DZD * N;              // 384*384
    float* EZ = EX + (size_t)N * N;                // 384*384
    float4* PACKX = (float4*)(EZ + (size_t)N * N); // 384*96 float4
    float4* PACKZ = PACKX + (size_t)N * NQUAD;     // 384*96 float4

    transpose_xz<<<12, 256, 0, stream>>>(X, Z, XT, ZT, out);
    exp_pairs<<<N, 192, 0, stream>>>(X, Z, XT, ZT, EX, EZ, PACKX, PACKZ);
    loss_k<<<2 * N, 192, 0, stream>>>(EX, EZ, PACKX, PACKZ, out);
}

// Round 17
// 32.643 us; speedup vs baseline: 1.1973x; 1.1922x over previous
//
#include <hip/hip_runtime.h>

#define N 384
#define DXD 128
#define DZD 32
#define NQUAD 96                   // quads of 4 b's per matrix (whole row)
#define NORM (2.0f / 1443840.0f)   // 2 / (n*K*(2n-3K-1)), n=384, K=5
#define CX 24.0f                   // exponent centers (cancel in sigma ratio)
#define CZ 12.0f

// ---------------------------------------------------------------------------
// Kernel A: LDS-tiled transpose, coalesced both sides; zeroes out[0].
__global__ void __launch_bounds__(256) transpose_xz(const float* __restrict__ X,
                                                    const float* __restrict__ Z,
                                                    float* __restrict__ XT,
                                                    float* __restrict__ ZT,
                                                    float* __restrict__ out) {
    __shared__ float tile[64][129];
    const int b = blockIdx.x;
    const int t = threadIdx.x;
    if (b == 0 && t == 0) out[0] = 0.f;

    if (b < 6) {
        const int R = b * 64;
        #pragma unroll
        for (int r0 = 0; r0 < 64; r0 += 8) {
            const int r = r0 + (t >> 5);
            const int c = (t & 31) * 4;
            float4 v = *reinterpret_cast<const float4*>(X + (size_t)(R + r) * DXD + c);
            tile[r][c] = v.x; tile[r][c + 1] = v.y; tile[r][c + 2] = v.z; tile[r][c + 3] = v.w;
        }
        __syncthreads();
        const int l = t & 63, w = t >> 6;
        #pragma unroll
        for (int k0 = 0; k0 < DXD; k0 += 4)
            XT[(size_t)(k0 + w) * N + R + l] = tile[l][k0 + w];
    } else {
        const int R = (b - 6) * 64;
        #pragma unroll
        for (int r0 = 0; r0 < 64; r0 += 32) {
            const int r = r0 + (t >> 3);
            const int c = (t & 7) * 4;
            float4 v = *reinterpret_cast<const float4*>(Z + (size_t)(R + r) * DZD + c);
            tile[r][c] = v.x; tile[r][c + 1] = v.y; tile[r][c + 2] = v.z; tile[r][c + 3] = v.w;
        }
        __syncthreads();
        const int l = t & 63, w = t >> 6;
        #pragma unroll
        for (int k0 = 0; k0 < DZD; k0 += 4)
            ZT[(size_t)(k0 + w) * N + R + l] = tile[l][k0 + w];
    }
}

// ---------------------------------------------------------------------------
// Kernel B: block (i, half): thread t -> a = half*192+t. One e per thread,
// write EX/EZ; build this half's 48 quads per matrix:
// PACKX[i][q] = (P0,S0,P1,S1), P=e0*e1, S=e0+e1 for pairs (4q,4q+1),(4q+2,4q+3).
__global__ void __launch_bounds__(192) exp_pairs(const float* __restrict__ X,
                                                 const float* __restrict__ Z,
                                                 const float* __restrict__ XT,
                                                 const float* __restrict__ ZT,
                                                 float* __restrict__ EX,
                                                 float* __restrict__ EZ,
                                                 float4* __restrict__ PACKX,
                                                 float4* __restrict__ PACKZ) {
    __shared__ float ex[192] __attribute__((aligned(16)));
    __shared__ float ez[192] __attribute__((aligned(16)));
    const int i = blockIdx.x >> 1;
    const int half = blockIdx.x & 1;
    const int t = threadIdx.x;
    const int a = half * 192 + t;

    const float* __restrict__ Xi = X + (size_t)i * DXD;   // uniform -> scalar path
    const float* __restrict__ Zi = Z + (size_t)i * DZD;

    float sq = 0.f;
    #pragma unroll 16
    for (int k = 0; k < DXD; ++k) {
        float v = XT[(size_t)k * N + a] - Xi[k];   // coalesced across lanes
        sq += v * v;
    }
    float dx = (sq > 1e-12f) ? sqrtf(sq) : 0.f;
    float exv = __expf(2.f * dx - CX);
    ex[t] = exv;
    EX[(size_t)i * N + a] = exv;

    float sqz = 0.f;
    #pragma unroll 16
    for (int k = 0; k < DZD; ++k) {
        float v = ZT[(size_t)k * N + a] - Zi[k];
        sqz += v * v;
    }
    float dz = (sqz > 1e-12f) ? sqrtf(sqz) : 0.f;
    float ezv = __expf(2.f * dz - CZ);
    ez[t] = ezv;
    EZ[(size_t)i * N + a] = ezv;
    __syncthreads();

    if (t < 48) {                  // X quads of this half
        const int q = t;
        float e0 = ex[4 * q], e1 = ex[4 * q + 1], e2 = ex[4 * q + 2], e3 = ex[4 * q + 3];
        PACKX[(size_t)i * NQUAD + half * 48 + q] =
            make_float4(e0 * e1, e0 + e1, e2 * e3, e2 + e3);
    } else if (t < 96) {           // Z quads of this half
        const int q = t - 48;
        float f0 = ez[4 * q], f1 = ez[4 * q + 1], f2 = ez[4 * q + 2], f3 = ez[4 * q + 3];
        PACKZ[(size_t)i * NQUAD + half * 48 + q] =
            make_float4(f0 * f1, f0 + f1, f2 * f3, f2 + f3);
    }
}

// ---------------------------------------------------------------------------
// Kernel C: loss, 6 waves/block for cross-pipe overlap. Block (i, half):
// threads t<192 handle a=half*192+t over b-quads [0,48); t>=192 same a over
// quads [48,96). Quad: d_j = P+S*ea+ea^2, n_j = 2P+S*ea;
// sum4 = (n1*d2+n2*d1)/(d1*d2) -> ~11 VALU + 1 rcp per 4 sigmoids.
__global__ void __launch_bounds__(384) loss_k(const float* __restrict__ EX,
                                              const float* __restrict__ EZ,
                                              const float4* __restrict__ PACKX,
                                              const float4* __restrict__ PACKZ,
                                              float* __restrict__ out) {
    __shared__ float4 px[NQUAD];
    __shared__ float4 pz[NQUAD];
    __shared__ float sxs[192];
    __shared__ float szs[192];
    __shared__ float red[3];
    const int i = blockIdx.x >> 1;
    const int half = blockIdx.x & 1;
    const int t = threadIdx.x;
    const int bh = (t >= 192) ? 1 : 0;   // wave-uniform (waves 0-2 vs 3-5)
    const int tt = t - 192 * bh;         // a-slot 0..191
    const int a = half * 192 + tt;

    if (t < NQUAD)            px[t] = PACKX[(size_t)i * NQUAD + t];
    else if (t < 2 * NQUAD)   pz[t - NQUAD] = PACKZ[(size_t)i * NQUAD + (t - NQUAD)];
    const float ea = EX[(size_t)i * N + a];   // coalesced (two identical halves)
    const float fa = EZ[(size_t)i * N + a];
    const float ea2 = ea * ea, fa2 = fa * fa;
    __syncthreads();

    float ax0 = 0.f, ax1 = 0.f, ax2 = 0.f, ax3 = 0.f;
    float az0 = 0.f, az1 = 0.f, az2 = 0.f, az3 = 0.f;

#define QUAD(c, s, s2, acc)                                                   \
    {                                                                         \
        float t1 = fmaf(s, c.y, c.x), t2 = fmaf(s, c.w, c.z);                 \
        float d1 = t1 + s2, d2 = t2 + s2;                                     \
        float n1 = t1 + c.x, n2 = t2 + c.z;                                   \
        float D = d1 * d2;                                                    \
        float Nn = fmaf(n2, d1, n1 * d2);                                     \
        acc = fmaf(Nn, __builtin_amdgcn_rcpf(D), acc);                        \
    }

    const int q0 = bh * 48;            // this thread's 48-quad window
    #pragma unroll 3
    for (int q = q0; q < q0 + 48; q += 4) {
        float4 cx0 = px[q + 0];        // uniform -> LDS broadcast
        float4 cx1 = px[q + 1];
        float4 cx2 = px[q + 2];
        float4 cx3 = px[q + 3];
        float4 cz0 = pz[q + 0];
        float4 cz1 = pz[q + 1];
        float4 cz2 = pz[q + 2];
        float4 cz3 = pz[q + 3];
        QUAD(cx0, ea, ea2, ax0)
        QUAD(cz0, fa, fa2, az0)
        QUAD(cx1, ea, ea2, ax1)
        QUAD(cz1, fa, fa2, az1)
        QUAD(cx2, ea, ea2, ax2)
        QUAD(cz2, fa, fa2, az2)
        QUAD(cx3, ea, ea2, ax3)
        QUAD(cz3, fa, fa2, az3)
    }
#undef QUAD
    float sx = (ax0 + ax1) + (ax2 + ax3);
    float sz = (az0 + az1) + (az2 + az3);

    // combine the two b-halves via LDS
    if (bh == 1) { sxs[tt] = sx; szs[tt] = sz; }
    __syncthreads();
    if (bh == 0) {
        sx += sxs[tt];
        sz += szs[tt];
        // intrusion = relu(1+sx-K); W = clamp((K+1-(1+sz))/K, 0, 1)
        float intr = fmaxf(sx - 4.f, 0.f);
        float W = fminf(fmaxf((5.f - sz) * 0.2f, 0.f), 1.f);
        float contrib = intr * (1.f - W);
        #pragma unroll
        for (int off = 32; off > 0; off >>= 1)
            contrib += __shfl_down(contrib, off, 64);
        const int lane = t & 63, w = t >> 6;
        if (lane == 0) red[w] = contrib;
    }
    __syncthreads();
    if (t == 0) atomicAdd(out, (red[0] + red[1] + red[2]) * NORM);
}

extern "C" void kernel_launch(void* const* d_in, const int* in_sizes, int n_in,
                              void* d_out, int out_size, void* d_ws, size_t ws_size,
                              hipStream_t stream) {
    const float* X = (const float*)d_in[0];   // (384, 128) f32
    const float* Z = (const float*)d_in[1];   // (384, 32)  f32
    float* out = (float*)d_out;

    float* XT = (float*)d_ws;                      // 128*384
    float* ZT = XT + (size_t)DXD * N;              // 32*384
    float* EX = ZT + (size_t)DZD * N;              // 384*384
    float* EZ = EX + (size_t)N * N;                // 384*384
    float4* PACKX = (float4*)(EZ + (size_t)N * N); // 384*96 float4
    float4* PACKZ = PACKX + (size_t)N * NQUAD;     // 384*96 float4

    transpose_xz<<<12, 256, 0, stream>>>(X, Z, XT, ZT, out);
    exp_pairs<<<2 * N, 192, 0, stream>>>(X, Z, XT, ZT, EX, EZ, PACKX, PACKZ);
    loss_k<<<2 * N, 384, 0, stream>>>(EX, EZ, PACKX, PACKZ, out);
}

// Round 18
// 31.237 us; speedup vs baseline: 1.2512x; 1.0450x over previous
//
#include <hip/hip_runtime.h>

#define N 384
#define DXD 128
#define DZD 32
#define NPAIR 192                  // pairs of 2 b's per matrix (whole row)
#define NORM (2.0f / 1443840.0f)   // 2 / (n*K*(2n-3K-1)), n=384, K=5
#define CX 24.0f                   // exponent centers (cancel in sigma ratio)
#define CZ 12.0f

typedef float f32x2 __attribute__((ext_vector_type(2)));

#define PKFMA(d, a, b, c) asm("v_pk_fma_f32 %0, %1, %2, %3" : "=v"(d) : "v"(a), "v"(b), "v"(c))
#define PKADD(d, a, b)    asm("v_pk_add_f32 %0, %1, %2"     : "=v"(d) : "v"(a), "v"(b))
#define PKMUL(d, a, b)    asm("v_pk_mul_f32 %0, %1, %2"     : "=v"(d) : "v"(a), "v"(b))

// ---------------------------------------------------------------------------
// Kernel A: LDS-tiled transpose, coalesced both sides; zeroes out[0].
__global__ void __launch_bounds__(256) transpose_xz(const float* __restrict__ X,
                                                    const float* __restrict__ Z,
                                                    float* __restrict__ XT,
                                                    float* __restrict__ ZT,
                                                    float* __restrict__ out) {
    __shared__ float tile[64][129];
    const int b = blockIdx.x;
    const int t = threadIdx.x;
    if (b == 0 && t == 0) out[0] = 0.f;

    if (b < 6) {
        const int R = b * 64;
        #pragma unroll
        for (int r0 = 0; r0 < 64; r0 += 8) {
            const int r = r0 + (t >> 5);
            const int c = (t & 31) * 4;
            float4 v = *reinterpret_cast<const float4*>(X + (size_t)(R + r) * DXD + c);
            tile[r][c] = v.x; tile[r][c + 1] = v.y; tile[r][c + 2] = v.z; tile[r][c + 3] = v.w;
        }
        __syncthreads();
        const int l = t & 63, w = t >> 6;
        #pragma unroll
        for (int k0 = 0; k0 < DXD; k0 += 4)
            XT[(size_t)(k0 + w) * N + R + l] = tile[l][k0 + w];
    } else {
        const int R = (b - 6) * 64;
        #pragma unroll
        for (int r0 = 0; r0 < 64; r0 += 32) {
            const int r = r0 + (t >> 3);
            const int c = (t & 7) * 4;
            float4 v = *reinterpret_cast<const float4*>(Z + (size_t)(R + r) * DZD + c);
            tile[r][c] = v.x; tile[r][c + 1] = v.y; tile[r][c + 2] = v.z; tile[r][c + 3] = v.w;
        }
        __syncthreads();
        const int l = t & 63, w = t >> 6;
        #pragma unroll
        for (int k0 = 0; k0 < DZD; k0 += 4)
            ZT[(size_t)(k0 + w) * N + R + l] = tile[l][k0 + w];
    }
}

// ---------------------------------------------------------------------------
// Kernel B: block (i, half): thread t -> a = half*192+t. One e per thread,
// write EX/EZ; build INTERLEAVED pair table for this half:
// PACKPS[i*NPAIR + half*96 + p] = (Px, Pz, Sx, Sz), P=e0*e1, S=e0+e1
// for pair p = (b=2p, 2p+1) within this half's local e-table.
__global__ void __launch_bounds__(192) exp_pairs(const float* __restrict__ X,
                                                 const float* __restrict__ Z,
                                                 const float* __restrict__ XT,
                                                 const float* __restrict__ ZT,
                                                 float* __restrict__ EX,
                                                 float* __restrict__ EZ,
                                                 float4* __restrict__ PACKPS) {
    __shared__ float ex[192] __attribute__((aligned(16)));
    __shared__ float ez[192] __attribute__((aligned(16)));
    const int i = blockIdx.x >> 1;
    const int half = blockIdx.x & 1;
    const int t = threadIdx.x;
    const int a = half * 192 + t;

    const float* __restrict__ Xi = X + (size_t)i * DXD;   // uniform -> scalar path
    const float* __restrict__ Zi = Z + (size_t)i * DZD;

    float sq = 0.f;
    #pragma unroll 16
    for (int k = 0; k < DXD; ++k) {
        float v = XT[(size_t)k * N + a] - Xi[k];   // coalesced across lanes
        sq += v * v;
    }
    float dx = (sq > 1e-12f) ? sqrtf(sq) : 0.f;
    float exv = __expf(2.f * dx - CX);
    ex[t] = exv;
    EX[(size_t)i * N + a] = exv;

    float sqz = 0.f;
    #pragma unroll 16
    for (int k = 0; k < DZD; ++k) {
        float v = ZT[(size_t)k * N + a] - Zi[k];
        sqz += v * v;
    }
    float dz = (sqz > 1e-12f) ? sqrtf(sqz) : 0.f;
    float ezv = __expf(2.f * dz - CZ);
    ez[t] = ezv;
    EZ[(size_t)i * N + a] = ezv;
    __syncthreads();

    if (t < 96) {
        float e0 = ex[2 * t], e1 = ex[2 * t + 1];
        float f0 = ez[2 * t], f1 = ez[2 * t + 1];
        PACKPS[(size_t)i * NPAIR + half * 96 + t] =
            make_float4(e0 * e1, f0 * f1, e0 + e1, f0 + f1);
    }
}

// ---------------------------------------------------------------------------
// Kernel C: loss with PACKED (X,Z) math. Per pair j: t=pk_fma(ee,S,P);
// d=t+ee2; n=t+P. Two pairs share one rcp per component:
// sum4 = (n0*d1 + n1*d0) / (d0*d1), done packed for X and Z simultaneously:
// ~9 pk + 2 rcp per 8 sigmoids. 6 waves/block; b-range split across wave-halves.
__global__ void __launch_bounds__(384) loss_k(const float* __restrict__ EX,
                                              const float* __restrict__ EZ,
                                              const float4* __restrict__ PACKPS,
                                              float* __restrict__ out) {
    __shared__ float4 ps[NPAIR];
    __shared__ float sxs[192];
    __shared__ float szs[192];
    __shared__ float red[3];
    const int i = blockIdx.x >> 1;
    const int half = blockIdx.x & 1;
    const int t = threadIdx.x;
    const int bh = (t >= 192) ? 1 : 0;   // wave-uniform (waves 0-2 vs 3-5)
    const int tt = t - 192 * bh;         // a-slot 0..191
    const int a = half * 192 + tt;

    if (t < NPAIR) ps[t] = PACKPS[(size_t)i * NPAIR + t];
    const float ea = EX[(size_t)i * N + a];   // coalesced (two identical halves)
    const float fa = EZ[(size_t)i * N + a];
    f32x2 ee;  ee.x = ea;       ee.y = fa;
    f32x2 ee2; ee2.x = ea * ea; ee2.y = fa * fa;
    __syncthreads();

    f32x2 acc0 = {0.f, 0.f}, acc1 = {0.f, 0.f}, acc2 = {0.f, 0.f}, acc3 = {0.f, 0.f};

    const int p0 = bh * 96;            // this thread's 96-pair window
    #pragma unroll 4
    for (int p = p0; p < p0 + 96; p += 8) {
        #pragma unroll
        for (int j = 0; j < 4; ++j) {
            float4 c0 = ps[p + 2 * j];        // (Px,Pz,Sx,Sz) uniform broadcast
            float4 c1 = ps[p + 2 * j + 1];
            f32x2 P0; P0.x = c0.x; P0.y = c0.y;
            f32x2 S0; S0.x = c0.z; S0.y = c0.w;
            f32x2 P1; P1.x = c1.x; P1.y = c1.y;
            f32x2 S1; S1.x = c1.z; S1.y = c1.w;
            f32x2 t0, t1, d0, d1, n0, n1, D, T, Nn, r;
            PKFMA(t0, ee, S0, P0);
            PKFMA(t1, ee, S1, P1);
            PKADD(d0, t0, ee2);
            PKADD(d1, t1, ee2);
            PKADD(n0, t0, P0);
            PKADD(n1, t1, P1);
            PKMUL(D, d0, d1);
            PKMUL(T, n0, d1);
            PKFMA(Nn, n1, d0, T);
            r.x = __builtin_amdgcn_rcpf(D.x);
            r.y = __builtin_amdgcn_rcpf(D.y);
            if (j == 0)      { PKFMA(acc0, Nn, r, acc0); }
            else if (j == 1) { PKFMA(acc1, Nn, r, acc1); }
            else if (j == 2) { PKFMA(acc2, Nn, r, acc2); }
            else             { PKFMA(acc3, Nn, r, acc3); }
        }
    }
    float sx = (acc0.x + acc1.x) + (acc2.x + acc3.x);
    float sz = (acc0.y + acc1.y) + (acc2.y + acc3.y);

    // combine the two b-halves via LDS
    if (bh == 1) { sxs[tt] = sx; szs[tt] = sz; }
    __syncthreads();
    if (bh == 0) {
        sx += sxs[tt];
        sz += szs[tt];
        // intrusion = relu(1+sx-K); W = clamp((K+1-(1+sz))/K, 0, 1)
        float intr = fmaxf(sx - 4.f, 0.f);
        float W = fminf(fmaxf((5.f - sz) * 0.2f, 0.f), 1.f);
        float contrib = intr * (1.f - W);
        #pragma unroll
        for (int off = 32; off > 0; off >>= 1)
            contrib += __shfl_down(contrib, off, 64);
        const int lane = t & 63, w = t >> 6;
        if (lane == 0) red[w] = contrib;
    }
    __syncthreads();
    if (t == 0) atomicAdd(out, (red[0] + red[1] + red[2]) * NORM);
}

extern "C" void kernel_launch(void* const* d_in, const int* in_sizes, int n_in,
                              void* d_out, int out_size, void* d_ws, size_t ws_size,
                              hipStream_t stream) {
    const float* X = (const float*)d_in[0];   // (384, 128) f32
    const float* Z = (const float*)d_in[1];   // (384, 32)  f32
    float* out = (float*)d_out;

    float* XT = (float*)d_ws;                      // 128*384
    float* ZT = XT + (size_t)DXD * N;              // 32*384
    float* EX = ZT + (size_t)DZD * N;              // 384*384
    float* EZ = EX + (size_t)N * N;                // 384*384
    float4* PACKPS = (float4*)(EZ + (size_t)N * N); // 384*192 float4

    transpose_xz<<<12, 256, 0, stream>>>(X, Z, XT, ZT, out);
    exp_pairs<<<2 * N, 192, 0, stream>>>(X, Z, XT, ZT, EX, EZ, PACKPS);
    loss_k<<<2 * N, 384, 0, stream>>>(EX, EZ, PACKPS, out);
}

// Round 19
// 28.142 us; speedup vs baseline: 1.3888x; 1.1100x over previous
//
#include <hip/hip_runtime.h>

#define N 384
#define DXD 128
#define DZD 32
#define NPAIR 192                  // pairs of 2 b's per matrix (whole row)
#define NORM (2.0f / 1443840.0f)   // 2 / (n*K*(2n-3K-1)), n=384, K=5
#define CX 24.0f                   // exponent centers (cancel in sigma ratio)
#define CZ 12.0f

typedef float f32x2 __attribute__((ext_vector_type(2)));

#define PKFMA(d, a, b, c) asm("v_pk_fma_f32 %0, %1, %2, %3" : "=v"(d) : "v"(a), "v"(b), "v"(c))
#define PKADD(d, a, b)    asm("v_pk_add_f32 %0, %1, %2"     : "=v"(d) : "v"(a), "v"(b))
#define PKMUL(d, a, b)    asm("v_pk_mul_f32 %0, %1, %2"     : "=v"(d) : "v"(a), "v"(b))

// ---------------------------------------------------------------------------
// Kernel A: LDS-tiled transpose, coalesced both sides; zeroes out[0].
__global__ void __launch_bounds__(256) transpose_xz(const float* __restrict__ X,
                                                    const float* __restrict__ Z,
                                                    float* __restrict__ XT,
                                                    float* __restrict__ ZT,
                                                    float* __restrict__ out) {
    __shared__ float tile[64][129];
    const int b = blockIdx.x;
    const int t = threadIdx.x;
    if (b == 0 && t == 0) out[0] = 0.f;

    if (b < 6) {
        const int R = b * 64;
        #pragma unroll
        for (int r0 = 0; r0 < 64; r0 += 8) {
            const int r = r0 + (t >> 5);
            const int c = (t & 31) * 4;
            float4 v = *reinterpret_cast<const float4*>(X + (size_t)(R + r) * DXD + c);
            tile[r][c] = v.x; tile[r][c + 1] = v.y; tile[r][c + 2] = v.z; tile[r][c + 3] = v.w;
        }
        __syncthreads();
        const int l = t & 63, w = t >> 6;
        #pragma unroll
        for (int k0 = 0; k0 < DXD; k0 += 4)
            XT[(size_t)(k0 + w) * N + R + l] = tile[l][k0 + w];
    } else {
        const int R = (b - 6) * 64;
        #pragma unroll
        for (int r0 = 0; r0 < 64; r0 += 32) {
            const int r = r0 + (t >> 3);
            const int c = (t & 7) * 4;
            float4 v = *reinterpret_cast<const float4*>(Z + (size_t)(R + r) * DZD + c);
            tile[r][c] = v.x; tile[r][c + 1] = v.y; tile[r][c + 2] = v.z; tile[r][c + 3] = v.w;
        }
        __syncthreads();
        const int l = t & 63, w = t >> 6;
        #pragma unroll
        for (int k0 = 0; k0 < DZD; k0 += 4)
            ZT[(size_t)(k0 + w) * N + R + l] = tile[l][k0 + w];
    }
}

// ---------------------------------------------------------------------------
// Kernel B: fully fused per-row loss. One block per row i (384 threads, 6 waves).
// Phase 1: e-tables built ONCE (thread t -> a=t), LDS only.
// Phase 1.5: interleaved pair table ps[p] = (Px,Pz,Sx,Sz), P=e0*e1, S=e0+e1.
// Phase 2: DUAL-A packed b-loop: thread handles a0=tt and a1=tt+192, sharing
// each ds_read_b128 between both a's math. Wave-halves split the pair range.
__global__ void __launch_bounds__(384) fused_loss(const float* __restrict__ X,
                                                  const float* __restrict__ Z,
                                                  const float* __restrict__ XT,
                                                  const float* __restrict__ ZT,
                                                  float* __restrict__ out) {
    __shared__ float ex[N] __attribute__((aligned(16)));
    __shared__ float ez[N] __attribute__((aligned(16)));
    __shared__ float4 ps[NPAIR];
    __shared__ float sxa0s[192], sza0s[192], sxa1s[192], sza1s[192];
    __shared__ float red[3];
    const int i = blockIdx.x;
    const int t = threadIdx.x;

    const float* __restrict__ Xi = X + (size_t)i * DXD;   // uniform -> scalar path
    const float* __restrict__ Zi = Z + (size_t)i * DZD;

    // phase 1: one e per thread (a = t), no duplication
    {
        float sq = 0.f;
        #pragma unroll 16
        for (int k = 0; k < DXD; ++k) {
            float v = XT[(size_t)k * N + t] - Xi[k];   // coalesced across 384 lanes
            sq += v * v;
        }
        float dx = (sq > 1e-12f) ? sqrtf(sq) : 0.f;
        ex[t] = __expf(2.f * dx - CX);

        float sqz = 0.f;
        #pragma unroll 16
        for (int k = 0; k < DZD; ++k) {
            float v = ZT[(size_t)k * N + t] - Zi[k];
            sqz += v * v;
        }
        float dz = (sqz > 1e-12f) ? sqrtf(sqz) : 0.f;
        ez[t] = __expf(2.f * dz - CZ);
    }
    __syncthreads();

    // phase 1.5: pair table (threads 0..191; stride-2 reads = 2-way, free)
    if (t < NPAIR) {
        float e0 = ex[2 * t], e1 = ex[2 * t + 1];
        float f0 = ez[2 * t], f1 = ez[2 * t + 1];
        ps[t] = make_float4(e0 * e1, f0 * f1, e0 + e1, f0 + f1);
    }
    __syncthreads();

    // phase 2: dual-a packed loop
    const int bh = (t >= 192) ? 1 : 0;   // wave-uniform (waves 0-2 vs 3-5)
    const int tt = t - 192 * bh;         // 0..191
    const int a0 = tt, a1 = tt + 192;

    const float ea0 = ex[a0], fa0 = ez[a0];
    const float ea1 = ex[a1], fa1 = ez[a1];
    f32x2 ee0;   ee0.x = ea0;        ee0.y = fa0;
    f32x2 ee0q;  ee0q.x = ea0 * ea0; ee0q.y = fa0 * fa0;
    f32x2 ee1;   ee1.x = ea1;        ee1.y = fa1;
    f32x2 ee1q;  ee1q.x = ea1 * ea1; ee1q.y = fa1 * fa1;

    f32x2 A0 = {0.f, 0.f}, A1 = {0.f, 0.f}, A2 = {0.f, 0.f}, A3 = {0.f, 0.f};
    f32x2 B0 = {0.f, 0.f}, B1 = {0.f, 0.f}, B2 = {0.f, 0.f}, B3 = {0.f, 0.f};

#define UNIT(c0, c1, eev, eeq, accm)                                          \
    {                                                                         \
        f32x2 P0; P0.x = c0.x; P0.y = c0.y;                                   \
        f32x2 S0; S0.x = c0.z; S0.y = c0.w;                                   \
        f32x2 P1; P1.x = c1.x; P1.y = c1.y;                                   \
        f32x2 S1; S1.x = c1.z; S1.y = c1.w;                                   \
        f32x2 t0, t1, d0, d1, n0, n1, D, T, Nn, r;                            \
        PKFMA(t0, eev, S0, P0);                                               \
        PKFMA(t1, eev, S1, P1);                                               \
        PKADD(d0, t0, eeq);                                                   \
        PKADD(d1, t1, eeq);                                                   \
        PKADD(n0, t0, P0);                                                    \
        PKADD(n1, t1, P1);                                                    \
        PKMUL(D, d0, d1);                                                     \
        PKMUL(T, n0, d1);                                                     \
        PKFMA(Nn, n1, d0, T);                                                 \
        r.x = __builtin_amdgcn_rcpf(D.x);                                     \
        r.y = __builtin_amdgcn_rcpf(D.y);                                     \
        PKFMA(accm, Nn, r, accm);                                             \
    }

    const int p0 = bh * 96;              // this half's 96 pairs = 48 units
    #pragma unroll 2
    for (int p = p0; p < p0 + 96; p += 8) {   // 12 iters x 4 units
        #pragma unroll
        for (int j = 0; j < 4; ++j) {
            float4 c0 = ps[p + 2 * j];        // uniform -> LDS broadcast
            float4 c1 = ps[p + 2 * j + 1];
            if (j == 0)      { UNIT(c0, c1, ee0, ee0q, A0) UNIT(c0, c1, ee1, ee1q, B0) }
            else if (j == 1) { UNIT(c0, c1, ee0, ee0q, A1) UNIT(c0, c1, ee1, ee1q, B1) }
            else if (j == 2) { UNIT(c0, c1, ee0, ee0q, A2) UNIT(c0, c1, ee1, ee1q, B2) }
            else             { UNIT(c0, c1, ee0, ee0q, A3) UNIT(c0, c1, ee1, ee1q, B3) }
        }
    }
#undef UNIT
    float sxa0 = (A0.x + A1.x) + (A2.x + A3.x);
    float sza0 = (A0.y + A1.y) + (A2.y + A3.y);
    float sxa1 = (B0.x + B1.x) + (B2.x + B3.x);
    float sza1 = (B0.y + B1.y) + (B2.y + B3.y);

    // combine the two b-halves via LDS
    if (bh == 1) { sxa0s[tt] = sxa0; sza0s[tt] = sza0; sxa1s[tt] = sxa1; sza1s[tt] = sza1; }
    __syncthreads();
    if (bh == 0) {
        sxa0 += sxa0s[tt];  sza0 += sza0s[tt];
        sxa1 += sxa1s[tt];  sza1 += sza1s[tt];
        // intrusion = relu(1+sx-K); W = clamp((K+1-(1+sz))/K, 0, 1)
        float i0 = fmaxf(sxa0 - 4.f, 0.f);
        float W0 = fminf(fmaxf((5.f - sza0) * 0.2f, 0.f), 1.f);
        float i1 = fmaxf(sxa1 - 4.f, 0.f);
        float W1 = fminf(fmaxf((5.f - sza1) * 0.2f, 0.f), 1.f);
        float contrib = i0 * (1.f - W0) + i1 * (1.f - W1);
        #pragma unroll
        for (int off = 32; off > 0; off >>= 1)
            contrib += __shfl_down(contrib, off, 64);
        const int lane = t & 63, w = t >> 6;
        if (lane == 0) red[w] = contrib;
    }
    __syncthreads();
    if (t == 0) atomicAdd(out, (red[0] + red[1] + red[2]) * NORM);
}

extern "C" void kernel_launch(void* const* d_in, const int* in_sizes, int n_in,
                              void* d_out, int out_size, void* d_ws, size_t ws_size,
                              hipStream_t stream) {
    const float* X = (const float*)d_in[0];   // (384, 128) f32
    const float* Z = (const float*)d_in[1];   // (384, 32)  f32
    float* out = (float*)d_out;

    float* XT = (float*)d_ws;                  // 128*384
    float* ZT = XT + (size_t)DXD * N;          // 32*384

    transpose_xz<<<12, 256, 0, stream>>>(X, Z, XT, ZT, out);
    fused_loss<<<N, 384, 0, stream>>>(X, Z, XT, ZT, out);
}

// Round 20
// 27.914 us; speedup vs baseline: 1.4001x; 1.0081x over previous
//
#include <hip/hip_runtime.h>

#define N 384
#define DXD 128
#define DZD 32
#define NPAIR 192                  // pairs of 2 b's per matrix (whole row)
#define NORM (2.0f / 1443840.0f)   // 2 / (n*K*(2n-3K-1)), n=384, K=5
#define CX 24.0f                   // exponent centers (cancel in sigma ratio)
#define CZ 12.0f

typedef float f32x2 __attribute__((ext_vector_type(2)));

#define PKFMA(d, a, b, c) asm("v_pk_fma_f32 %0, %1, %2, %3" : "=v"(d) : "v"(a), "v"(b), "v"(c))
#define PKADD(d, a, b)    asm("v_pk_add_f32 %0, %1, %2"     : "=v"(d) : "v"(a), "v"(b))
#define PKMUL(d, a, b)    asm("v_pk_mul_f32 %0, %1, %2"     : "=v"(d) : "v"(a), "v"(b))

// ---------------------------------------------------------------------------
// Kernel A: LDS-tiled transpose, coalesced both sides; zeroes out[0].
__global__ void __launch_bounds__(256) transpose_xz(const float* __restrict__ X,
                                                    const float* __restrict__ Z,
                                                    float* __restrict__ XT,
                                                    float* __restrict__ ZT,
                                                    float* __restrict__ out) {
    __shared__ float tile[64][129];
    const int b = blockIdx.x;
    const int t = threadIdx.x;
    if (b == 0 && t == 0) out[0] = 0.f;

    if (b < 6) {
        const int R = b * 64;
        #pragma unroll
        for (int r0 = 0; r0 < 64; r0 += 8) {
            const int r = r0 + (t >> 5);
            const int c = (t & 31) * 4;
            float4 v = *reinterpret_cast<const float4*>(X + (size_t)(R + r) * DXD + c);
            tile[r][c] = v.x; tile[r][c + 1] = v.y; tile[r][c + 2] = v.z; tile[r][c + 3] = v.w;
        }
        __syncthreads();
        const int l = t & 63, w = t >> 6;
        #pragma unroll
        for (int k0 = 0; k0 < DXD; k0 += 4)
            XT[(size_t)(k0 + w) * N + R + l] = tile[l][k0 + w];
    } else {
        const int R = (b - 6) * 64;
        #pragma unroll
        for (int r0 = 0; r0 < 64; r0 += 32) {
            const int r = r0 + (t >> 3);
            const int c = (t & 7) * 4;
            float4 v = *reinterpret_cast<const float4*>(Z + (size_t)(R + r) * DZD + c);
            tile[r][c] = v.x; tile[r][c + 1] = v.y; tile[r][c + 2] = v.z; tile[r][c + 3] = v.w;
        }
        __syncthreads();
        const int l = t & 63, w = t >> 6;
        #pragma unroll
        for (int k0 = 0; k0 < DZD; k0 += 4)
            ZT[(size_t)(k0 + w) * N + R + l] = tile[l][k0 + w];
    }
}

// ---------------------------------------------------------------------------
// Kernel B: fused per-row loss, QUAD-A. One block per row i (384 threads).
// Phase 1: e-tables once (t -> a=t). Phase 1.5: pair table (Px,Pz,Sx,Sz).
// Phase 2: thread (qh = t/96, tt = t%96) handles a in {tt, tt+96, tt+192,
// tt+288} over b-window qh (48 pairs) -> each ds_read_b128 feeds 4 UNITs.
// Phase 3: per-a combine across the 4 windows, nonlinearity, reduce, atomic.
__global__ void __launch_bounds__(384) fused_loss(const float* __restrict__ X,
                                                  const float* __restrict__ Z,
                                                  const float* __restrict__ XT,
                                                  const float* __restrict__ ZT,
                                                  float* __restrict__ out) {
    __shared__ float ex[N] __attribute__((aligned(16)));
    __shared__ float ez[N] __attribute__((aligned(16)));
    __shared__ float4 ps[NPAIR];
    __shared__ float sxp[4][N];
    __shared__ float szp[4][N];
    __shared__ float red[6];
    const int i = blockIdx.x;
    const int t = threadIdx.x;

    const float* __restrict__ Xi = X + (size_t)i * DXD;   // uniform -> scalar path
    const float* __restrict__ Zi = Z + (size_t)i * DZD;

    // phase 1: one e per thread (a = t)
    {
        float sq = 0.f;
        #pragma unroll 16
        for (int k = 0; k < DXD; ++k) {
            float v = XT[(size_t)k * N + t] - Xi[k];   // coalesced across lanes
            sq += v * v;
        }
        float dx = (sq > 1e-12f) ? sqrtf(sq) : 0.f;
        ex[t] = __expf(2.f * dx - CX);

        float sqz = 0.f;
        #pragma unroll 16
        for (int k = 0; k < DZD; ++k) {
            float v = ZT[(size_t)k * N + t] - Zi[k];
            sqz += v * v;
        }
        float dz = (sqz > 1e-12f) ? sqrtf(sqz) : 0.f;
        ez[t] = __expf(2.f * dz - CZ);
    }
    __syncthreads();

    // phase 1.5: pair table (stride-2 reads = 2-way alias, free)
    if (t < NPAIR) {
        float e0 = ex[2 * t], e1 = ex[2 * t + 1];
        float f0 = ez[2 * t], f1 = ez[2 * t + 1];
        ps[t] = make_float4(e0 * e1, f0 * f1, e0 + e1, f0 + f1);
    }
    __syncthreads();

    // phase 2: quad-a over this thread's 48-pair window
    const int qh = t / 96;             // window 0..3 (uniform trip count)
    const int tt = t - 96 * qh;        // 0..95
    const int a0 = tt, a1 = tt + 96, a2 = tt + 192, a3 = tt + 288;

    f32x2 ee0;  ee0.x = ex[a0]; ee0.y = ez[a0];
    f32x2 ee1;  ee1.x = ex[a1]; ee1.y = ez[a1];
    f32x2 ee2;  ee2.x = ex[a2]; ee2.y = ez[a2];
    f32x2 ee3;  ee3.x = ex[a3]; ee3.y = ez[a3];
    f32x2 eq0, eq1, eq2, eq3;
    PKMUL(eq0, ee0, ee0);
    PKMUL(eq1, ee1, ee1);
    PKMUL(eq2, ee2, ee2);
    PKMUL(eq3, ee3, ee3);

    f32x2 A0 = {0.f, 0.f}, A1 = {0.f, 0.f}, A2 = {0.f, 0.f}, A3 = {0.f, 0.f};

#define UNIT(c0, c1, eev, eeq, accm)                                          \
    {                                                                         \
        f32x2 P0; P0.x = c0.x; P0.y = c0.y;                                   \
        f32x2 S0; S0.x = c0.z; S0.y = c0.w;                                   \
        f32x2 P1; P1.x = c1.x; P1.y = c1.y;                                   \
        f32x2 S1; S1.x = c1.z; S1.y = c1.w;                                   \
        f32x2 t0, t1, d0, d1, n0, n1, D, T, Nn, r;                            \
        PKFMA(t0, eev, S0, P0);                                               \
        PKFMA(t1, eev, S1, P1);                                               \
        PKADD(d0, t0, eeq);                                                   \
        PKADD(d1, t1, eeq);                                                   \
        PKADD(n0, t0, P0);                                                    \
        PKADD(n1, t1, P1);                                                    \
        PKMUL(D, d0, d1);                                                     \
        PKMUL(T, n0, d1);                                                     \
        PKFMA(Nn, n1, d0, T);                                                 \
        r.x = __builtin_amdgcn_rcpf(D.x);                                     \
        r.y = __builtin_amdgcn_rcpf(D.y);                                     \
        PKFMA(accm, Nn, r, accm);                                             \
    }

    const int p0 = qh * 48;            // this window's 48 pairs = 24 units
    #pragma unroll 3
    for (int p = p0; p < p0 + 48; p += 4) {   // 12 iters x 2 units
        #pragma unroll
        for (int j = 0; j < 2; ++j) {
            float4 c0 = ps[p + 2 * j];        // shared by 4 a's
            float4 c1 = ps[p + 2 * j + 1];
            UNIT(c0, c1, ee0, eq0, A0)
            UNIT(c0, c1, ee1, eq1, A1)
            UNIT(c0, c1, ee2, eq2, A2)
            UNIT(c0, c1, ee3, eq3, A3)
        }
    }
#undef UNIT

    sxp[qh][a0] = A0.x;  szp[qh][a0] = A0.y;
    sxp[qh][a1] = A1.x;  szp[qh][a1] = A1.y;
    sxp[qh][a2] = A2.x;  szp[qh][a2] = A2.y;
    sxp[qh][a3] = A3.x;  szp[qh][a3] = A3.y;
    __syncthreads();

    // phase 3: thread t finalizes a = t
    {
        float sx = (sxp[0][t] + sxp[1][t]) + (sxp[2][t] + sxp[3][t]);
        float sz = (szp[0][t] + szp[1][t]) + (szp[2][t] + szp[3][t]);
        // intrusion = relu(1+sx-K); W = clamp((K+1-(1+sz))/K, 0, 1)
        float intr = fmaxf(sx - 4.f, 0.f);
        float W = fminf(fmaxf((5.f - sz) * 0.2f, 0.f), 1.f);
        float contrib = intr * (1.f - W);
        #pragma unroll
        for (int off = 32; off > 0; off >>= 1)
            contrib += __shfl_down(contrib, off, 64);
        const int lane = t & 63, w = t >> 6;
        if (lane == 0) red[w] = contrib;
    }
    __syncthreads();
    if (t == 0) {
        float s = ((red[0] + red[1]) + (red[2] + red[3])) + (red[4] + red[5]);
        atomicAdd(out, s * NORM);
    }
}

extern "C" void kernel_launch(void* const* d_in, const int* in_sizes, int n_in,
                              void* d_out, int out_size, void* d_ws, size_t ws_size,
                              hipStream_t stream) {
    const float* X = (const float*)d_in[0];   // (384, 128) f32
    const float* Z = (const float*)d_in[1];   // (384, 32)  f32
    float* out = (float*)d_out;

    float* XT = (float*)d_ws;                  // 128*384
    float* ZT = XT + (size_t)DXD * N;          // 32*384

    transpose_xz<<<12, 256, 0, stream>>>(X, Z, XT, ZT, out);
    fused_loss<<<N, 384, 0, stream>>>(X, Z, XT, ZT, out);
}